// Round 1
// baseline (1070.383 us; speedup 1.0000x reference)
//
#include <hip/hip_runtime.h>
#include <hip/hip_bf16.h>

// Problem constants
#define B_   32
#define N_   3200          // H*W*IC = 10*10*32
#define C_   20            // NUM_CAPSULE
#define A_   64            // NUM_ATOMS
#define IA_  32            // input atoms (K of votes GEMM)
#define CA_  1280          // C_*A_

typedef unsigned short u16;
typedef unsigned int   u32;

__device__ __forceinline__ u16 f2bf(float f) {
    union { float f; u32 u; } v; v.f = f;
    u32 r = v.u + 0x7FFFu + ((v.u >> 16) & 1u);   // RNE
    return (u16)(r >> 16);
}

// ---------------------------------------------------------------------------
// Kernel A: votes[b,n,o] = sum_i x[b,n,i] * W[n,i,o]  (store bf16)
// Also accumulates S[b,o] = sum_n votes[b,n,o] into preact (for iter 1:
// route = 1/20 uniform, so preact1 = S/20 + bias, applied in squash).
// Block: 256 threads, handles (n-tile of 16) x (o-chunk of 128) for ALL 32 b.
// ---------------------------------------------------------------------------
#define NT_ 16
#define OC_ 128

__global__ __launch_bounds__(256) void votes_kernel(
    const float* __restrict__ x,     // [B, N, IA]
    const float* __restrict__ W,     // [N, IA, CA]
    u16*   __restrict__ votes,       // [B, N, CA] bf16
    float* __restrict__ preact)      // [B, CA] accumulated
{
    __shared__ __align__(16) float xs[B_][IA_];     // 4 KB
    __shared__ __align__(16) float ws[IA_ * OC_];   // 16 KB, flat [i*128+o]

    const int t     = threadIdx.x;
    const int oc    = blockIdx.x % 10;
    const int ntile = blockIdx.x / 10;
    const int n0    = ntile * NT_;
    const int obase = oc * OC_;

    const int ol = (t & 31) * 4;       // local o, thread covers [ol, ol+4)
    const int b0 = (t >> 5) * 4;       // thread covers b in [b0, b0+4)

    float S[4][4];
    #pragma unroll
    for (int jb = 0; jb < 4; ++jb)
        #pragma unroll
        for (int jo = 0; jo < 4; ++jo) S[jb][jo] = 0.f;

    for (int nn = 0; nn < NT_; ++nn) {
        const int n = n0 + nn;
        __syncthreads();
        // stage x[all b, n, :]  (1024 words, contiguous LDS, conflict-free)
        {
            const int b  = t >> 3;
            const int i4 = (t & 7) * 4;
            *(float4*)&xs[b][i4] =
                *(const float4*)&x[((size_t)b * N_ + n) * IA_ + i4];
        }
        // stage W[n, :, obase..obase+128) (4096 words, contiguous LDS order)
        {
            #pragma unroll
            for (int k = 0; k < 4; ++k) {
                const int f = k * 1024 + t * 4;       // flat LDS word index
                const int i = f >> 7;                 // row
                const int o = f & 127;                // col
                ws[f] = 0.f; // placeholder overwritten below (kept simple)
                *(float4*)&ws[f] =
                    *(const float4*)&W[((size_t)n * IA_ + i) * CA_ + obase + o];
            }
        }
        __syncthreads();

        float v[4][4];
        #pragma unroll
        for (int jb = 0; jb < 4; ++jb)
            #pragma unroll
            for (int jo = 0; jo < 4; ++jo) v[jb][jo] = 0.f;

        #pragma unroll
        for (int iq = 0; iq < 8; ++iq) {
            float4 xq[4], wq[4];
            #pragma unroll
            for (int j = 0; j < 4; ++j)
                xq[j] = *(const float4*)&xs[b0 + j][iq * 4];
            #pragma unroll
            for (int j = 0; j < 4; ++j)
                wq[j] = *(const float4*)&ws[(iq * 4 + j) * OC_ + ol];
            #pragma unroll
            for (int jb = 0; jb < 4; ++jb) {
                #pragma unroll
                for (int jo = 0; jo < 4; ++jo) {
                    v[jb][jo] += xq[jb].x * wq[0][jo];
                    v[jb][jo] += xq[jb].y * wq[1][jo];
                    v[jb][jo] += xq[jb].z * wq[2][jo];
                    v[jb][jo] += xq[jb].w * wq[3][jo];
                }
            }
        }
        // store bf16 votes + accumulate S
        #pragma unroll
        for (int jb = 0; jb < 4; ++jb) {
            ushort4 pk;
            pk.x = f2bf(v[jb][0]); pk.y = f2bf(v[jb][1]);
            pk.z = f2bf(v[jb][2]); pk.w = f2bf(v[jb][3]);
            S[jb][0] += v[jb][0]; S[jb][1] += v[jb][1];
            S[jb][2] += v[jb][2]; S[jb][3] += v[jb][3];
            *(ushort4*)&votes[((size_t)(b0 + jb) * N_ + n) * CA_ + obase + ol] = pk;
        }
    }
    #pragma unroll
    for (int jb = 0; jb < 4; ++jb)
        #pragma unroll
        for (int jo = 0; jo < 4; ++jo)
            atomicAdd(&preact[(size_t)(b0 + jb) * CA_ + obase + ol + jo], S[jb][jo]);
}

// ---------------------------------------------------------------------------
// Kernel B: one routing pass (T=2 or T=3).
//   d[c]      = sum_a votes[b,n,c,a]*act[b,c,a]
//   lg[c]     = (T==3 ? logits_in : 0) + d[c]        (this is logits_{T-1})
//   route     = softmax_c(lg)
//   preact   += route[c]*votes[b,n,c,a]              (atomics at the end)
//   T==2 also stores lg -> logits_out for the T==3 pass.
// One wave per (b,n) task; lane layout: c = lane&31 (valid c<20), half=lane>>5
// owning a in [half*32, half*32+32).
// ---------------------------------------------------------------------------
template <int T>
__global__ __launch_bounds__(256) void route_kernel(
    const u16*  __restrict__ votes,      // [B,N,CA] bf16
    const float* __restrict__ act,       // [B,C,A]
    const float* __restrict__ logits_in, // [B,N,C] (T==3)
    float* __restrict__ logits_out,      // [B,N,C] (T==2)
    float* __restrict__ preact)          // [B,CA]
{
    const int t    = threadIdx.x;
    const int lane = t & 63;
    const int gw   = (blockIdx.x << 2) + (t >> 6);   // 5120 waves
    const int b     = gw / 160;                       // 160 waves per b
    const int slice = gw % 160;                       // 20 n's per wave
    const int c    = lane & 31;
    const int half = lane >> 5;
    const int ceff = (c < C_) ? c : (C_ - 1);
    const bool cval = (c < C_);
    const bool v0   = cval && (half == 0);

    float av[32];
    {
        const float* ap = &act[(size_t)b * CA_ + ceff * A_ + half * 32];
        #pragma unroll
        for (int j = 0; j < 8; ++j) {
            float4 f = *(const float4*)(ap + 4 * j);
            av[4*j+0] = f.x; av[4*j+1] = f.y; av[4*j+2] = f.z; av[4*j+3] = f.w;
        }
    }
    float acc[32];
    #pragma unroll
    for (int j = 0; j < 32; ++j) acc[j] = 0.f;

    for (int k = 0; k < 20; ++k) {
        const int n = slice * 20 + k;
        const size_t base = ((size_t)b * N_ + n) * CA_ + ceff * A_ + half * 32;
        float vf[32];
        float dot = 0.f;
        #pragma unroll
        for (int j = 0; j < 4; ++j) {
            uint4 q = *(const uint4*)(votes + base + j * 8);
            u32 uu0 = q.x, uu1 = q.y, uu2 = q.z, uu3 = q.w;
            float f0, f1;
            f0 = __uint_as_float(uu0 << 16); f1 = __uint_as_float(uu0 & 0xffff0000u);
            vf[j*8+0] = f0; vf[j*8+1] = f1; dot += f0*av[j*8+0] + f1*av[j*8+1];
            f0 = __uint_as_float(uu1 << 16); f1 = __uint_as_float(uu1 & 0xffff0000u);
            vf[j*8+2] = f0; vf[j*8+3] = f1; dot += f0*av[j*8+2] + f1*av[j*8+3];
            f0 = __uint_as_float(uu2 << 16); f1 = __uint_as_float(uu2 & 0xffff0000u);
            vf[j*8+4] = f0; vf[j*8+5] = f1; dot += f0*av[j*8+4] + f1*av[j*8+5];
            f0 = __uint_as_float(uu3 << 16); f1 = __uint_as_float(uu3 & 0xffff0000u);
            vf[j*8+6] = f0; vf[j*8+7] = f1; dot += f0*av[j*8+6] + f1*av[j*8+7];
        }
        dot += __shfl_xor(dot, 32);
        float lg = -3.0e38f;
        if (v0) {
            lg = dot;
            if (T == 3) lg += logits_in[((size_t)b * N_ + n) * C_ + c];
        }
        float mx = lg;
        #pragma unroll
        for (int s = 32; s >= 1; s >>= 1) mx = fmaxf(mx, __shfl_xor(mx, s));
        float e = v0 ? __expf(lg - mx) : 0.f;
        float sum = e;
        #pragma unroll
        for (int s = 32; s >= 1; s >>= 1) sum += __shfl_xor(sum, s);
        const float route = e / sum;             // valid on lanes 0..19
        if (T == 2 && v0)
            logits_out[((size_t)b * N_ + n) * C_ + c] = lg;
        const float r = __shfl(route, c);        // route[c] lives in lane c
        #pragma unroll
        for (int j = 0; j < 32; ++j) acc[j] += r * vf[j];
    }
    if (cval) {
        float* pp = &preact[(size_t)b * CA_ + c * A_ + half * 32];
        #pragma unroll
        for (int j = 0; j < 32; ++j) atomicAdd(pp + j, acc[j]);
    }
}

// ---------------------------------------------------------------------------
// Squash: out[b,c,a] = squash(preact*scale + bias). One wave per (b,c).
// ---------------------------------------------------------------------------
__global__ __launch_bounds__(256) void squash_kernel(
    const float* __restrict__ preact, const float* __restrict__ bias,
    float* __restrict__ out, float scale)
{
    const int gw   = (blockIdx.x << 2) + (threadIdx.x >> 6);  // 640 waves
    const int lane = threadIdx.x & 63;
    const int b = gw / C_;
    const int c = gw % C_;
    const float p = preact[(size_t)b * CA_ + c * A_ + lane] * scale
                  + bias[c * A_ + lane];
    float sq = p * p;
    #pragma unroll
    for (int s = 32; s >= 1; s >>= 1) sq += __shfl_xor(sq, s);
    const float nrm = sqrtf(sq);
    out[(size_t)b * CA_ + c * A_ + lane] = p * nrm / (1.f + sq);
}

// ---------------------------------------------------------------------------
extern "C" void kernel_launch(void* const* d_in, const int* in_sizes, int n_in,
                              void* d_out, int out_size, void* d_ws, size_t ws_size,
                              hipStream_t stream) {
    const float* x    = (const float*)d_in[0];   // [B,H,W,IC,IA] = [B,N,IA]
    const float* W    = (const float*)d_in[1];   // [N,IA,CA]
    const float* bias = (const float*)d_in[2];   // [C,A]
    float* out = (float*)d_out;

    // workspace layout (needs ~271 MB)
    char* ws = (char*)d_ws;
    u16*   votes  = (u16*)ws;                                    // 262,144,000 B
    float* logits = (float*)(ws + 262144000ull);                 //   8,192,000 B
    float* preact = (float*)(ws + 262144000ull + 8192000ull);    //     163,840 B
    float* act    = (float*)(ws + 262144000ull + 8192000ull + 163840ull);

    const size_t PRE_BYTES = (size_t)B_ * CA_ * sizeof(float);

    // iter 1: votes + S (uniform route), squash with scale 1/20
    hipMemsetAsync(preact, 0, PRE_BYTES, stream);
    votes_kernel<<<2000, 256, 0, stream>>>(x, W, votes, preact);
    squash_kernel<<<160, 256, 0, stream>>>(preact, bias, act, 1.f / (float)C_);

    // iter 2
    hipMemsetAsync(preact, 0, PRE_BYTES, stream);
    route_kernel<2><<<1280, 256, 0, stream>>>(votes, act, nullptr, logits, preact);
    squash_kernel<<<160, 256, 0, stream>>>(preact, bias, act, 1.f);

    // iter 3 (logits update of iter 3 is dead in the reference -> skipped)
    hipMemsetAsync(preact, 0, PRE_BYTES, stream);
    route_kernel<3><<<1280, 256, 0, stream>>>(votes, act, logits, nullptr, preact);
    squash_kernel<<<160, 256, 0, stream>>>(preact, bias, out, 1.f);
}

// Round 2
// 332.134 us; speedup vs baseline: 3.2227x; 3.2227x over previous
//
#include <hip/hip_runtime.h>
#include <hip/hip_bf16.h>

// Problem constants
#define B_   32
#define N_   3200          // H*W*IC
#define C_   20
#define A_   64
#define IA_  32
#define CA_  1280          // C_*A_
#define NTILE_ 32          // n's per votes block
#define NGRP_  100         // N_/NTILE_
#define RSLICE_ 40         // route slice-groups per b (4 waves each -> 160 slices/b)

typedef unsigned short u16;
typedef unsigned int   u32;

__device__ __forceinline__ u16 f2bf(float f) {
    union { float f; u32 u; } v; v.f = f;
    u32 r = v.u + 0x7FFFu + ((v.u >> 16) & 1u);   // RNE
    return (u16)(r >> 16);
}
__device__ __forceinline__ void unp(u32 u, float& lo, float& hi) {
    lo = __uint_as_float(u << 16);
    hi = __uint_as_float(u & 0xffff0000u);
}

// ---------------------------------------------------------------------------
// Kernel A: votes[b,n,o] = sum_i x[b,n,i]*W[n,i,o], bf16 store.
// Also per-block partial of S[b,o] = sum_n votes (no atomics):
//   partial[b][g][o], g = n-tile index (NGRP_ tiles of NTILE_ n's).
// ---------------------------------------------------------------------------
#define OC_ 128

__global__ __launch_bounds__(256) void votes_kernel(
    const float* __restrict__ x,     // [B, N, IA]
    const float* __restrict__ W,     // [N, IA, CA]
    u16*   __restrict__ votes,       // [B, N, CA] bf16
    float* __restrict__ partial)     // [B, NGRP_, CA]
{
    __shared__ __align__(16) float xs[B_][IA_];     // 4 KB
    __shared__ __align__(16) float ws[IA_ * OC_];   // 16 KB

    const int t     = threadIdx.x;
    const int oc    = blockIdx.x % 10;
    const int g     = blockIdx.x / 10;       // 0..99
    const int n0    = g * NTILE_;
    const int obase = oc * OC_;

    const int ol = (t & 31) * 4;
    const int b0 = (t >> 5) * 4;

    float S[4][4];
    #pragma unroll
    for (int jb = 0; jb < 4; ++jb)
        #pragma unroll
        for (int jo = 0; jo < 4; ++jo) S[jb][jo] = 0.f;

    for (int nn = 0; nn < NTILE_; ++nn) {
        const int n = n0 + nn;
        __syncthreads();
        {
            const int b  = t >> 3;
            const int i4 = (t & 7) * 4;
            *(float4*)&xs[b][i4] =
                *(const float4*)&x[((size_t)b * N_ + n) * IA_ + i4];
        }
        {
            #pragma unroll
            for (int k = 0; k < 4; ++k) {
                const int f = k * 1024 + t * 4;
                const int i = f >> 7;
                const int o = f & 127;
                *(float4*)&ws[f] =
                    *(const float4*)&W[((size_t)n * IA_ + i) * CA_ + obase + o];
            }
        }
        __syncthreads();

        float v[4][4];
        #pragma unroll
        for (int jb = 0; jb < 4; ++jb)
            #pragma unroll
            for (int jo = 0; jo < 4; ++jo) v[jb][jo] = 0.f;

        #pragma unroll
        for (int iq = 0; iq < 8; ++iq) {
            float4 xq[4], wq[4];
            #pragma unroll
            for (int j = 0; j < 4; ++j)
                xq[j] = *(const float4*)&xs[b0 + j][iq * 4];
            #pragma unroll
            for (int j = 0; j < 4; ++j)
                wq[j] = *(const float4*)&ws[(iq * 4 + j) * OC_ + ol];
            #pragma unroll
            for (int jb = 0; jb < 4; ++jb) {
                #pragma unroll
                for (int jo = 0; jo < 4; ++jo) {
                    v[jb][jo] += xq[jb].x * wq[0][jo];
                    v[jb][jo] += xq[jb].y * wq[1][jo];
                    v[jb][jo] += xq[jb].z * wq[2][jo];
                    v[jb][jo] += xq[jb].w * wq[3][jo];
                }
            }
        }
        #pragma unroll
        for (int jb = 0; jb < 4; ++jb) {
            ushort4 pk;
            pk.x = f2bf(v[jb][0]); pk.y = f2bf(v[jb][1]);
            pk.z = f2bf(v[jb][2]); pk.w = f2bf(v[jb][3]);
            S[jb][0] += v[jb][0]; S[jb][1] += v[jb][1];
            S[jb][2] += v[jb][2]; S[jb][3] += v[jb][3];
            *(ushort4*)&votes[((size_t)(b0 + jb) * N_ + n) * CA_ + obase + ol] = pk;
        }
    }
    #pragma unroll
    for (int jb = 0; jb < 4; ++jb) {
        float4 s4 = make_float4(S[jb][0], S[jb][1], S[jb][2], S[jb][3]);
        *(float4*)&partial[((size_t)(b0 + jb) * NGRP_ + g) * CA_ + obase + ol] = s4;
    }
}

// ---------------------------------------------------------------------------
// Kernel B: fused routing pass. Flat-chunk layout:
//   lane owns 16B chunks {lane, lane+64, lane+128(lane<32)} of each 2560B
//   votes row -> fully coalesced loads; chunk k belongs to capsule k/8,
//   so each dot is a 3-level shuffle reduce over 8 consecutive lanes.
// Per-block (4 waves, same b) LDS reduce -> partial[b][sgrp][1280], no atomics.
// ---------------------------------------------------------------------------
template <int T>
__global__ __launch_bounds__(256) __attribute__((amdgpu_waves_per_eu(3)))
void route_kernel(
    const u16*  __restrict__ votes,      // [B,N,CA] bf16
    const float* __restrict__ act,       // [B,C,A]
    const float* __restrict__ logits_in, // [B,N,C] (T==3)
    float* __restrict__ logits_out,      // [B,N,C] (T==2)
    float* __restrict__ partial)         // [B,RSLICE_,CA]
{
    __shared__ float red[4][CA_];        // 20 KB
    const int t    = threadIdx.x;
    const int lane = t & 63;
    const int w    = t >> 6;
    const int b    = blockIdx.x / RSLICE_;
    const int sgrp = blockIdx.x % RSLICE_;
    const int slice = sgrp * 4 + w;      // 0..159, 20 n's each
    const int c0   = lane >> 3;          // capsule of chunk slot 0 (0..7)
    const bool has2 = lane < 32;         // slot 2 -> capsules 16..19
    const bool isL  = (lane & 7) == 0;
    const int off0 = lane * 8;           // u16 offsets within a row
    const int off1 = off0 + 512;
    const int off2 = has2 ? off0 + 1024 : 0;

    // act fragments for this lane's three capsules (av2 garbage on lanes>=32,
    // but its routing weight is forced to 0 there).
    float av0[8], av1[8], av2[8];
    {
        const float* ab = act + (size_t)b * CA_;
        #pragma unroll
        for (int j = 0; j < 2; ++j) {
            float4 f;
            f = *(const float4*)(ab + off0 + 4 * j);
            av0[4*j] = f.x; av0[4*j+1] = f.y; av0[4*j+2] = f.z; av0[4*j+3] = f.w;
            f = *(const float4*)(ab + off1 + 4 * j);
            av1[4*j] = f.x; av1[4*j+1] = f.y; av1[4*j+2] = f.z; av1[4*j+3] = f.w;
            f = *(const float4*)(ab + off2 + 4 * j);
            av2[4*j] = f.x; av2[4*j+1] = f.y; av2[4*j+2] = f.z; av2[4*j+3] = f.w;
        }
    }
    float ac0[8], ac1[8], ac2[8];
    #pragma unroll
    for (int j = 0; j < 8; ++j) { ac0[j] = 0.f; ac1[j] = 0.f; ac2[j] = 0.f; }

    const u16* vrow = votes + ((size_t)b * N_ + (size_t)slice * 20) * CA_;
    uint4 qa0 = *(const uint4*)(vrow + off0);
    uint4 qa1 = *(const uint4*)(vrow + off1);
    uint4 qa2 = *(const uint4*)(vrow + off2);

    const float* lgp = (T == 3) ? (logits_in  + ((size_t)b * N_ + (size_t)slice * 20) * C_) : nullptr;
    float*       lsp = (T == 2) ? (logits_out + ((size_t)b * N_ + (size_t)slice * 20) * C_) : nullptr;

    for (int k = 0; k < 20; ++k) {
        // prefetch next row (last iter re-loads same row; harmless)
        const u16* vnx = vrow + (size_t)((k < 19) ? (k + 1) : k) * CA_;
        uint4 qb0 = *(const uint4*)(vnx + off0);
        uint4 qb1 = *(const uint4*)(vnx + off1);
        uint4 qb2 = *(const uint4*)(vnx + off2);

        float v0[8], v1[8], v2[8];
        unp(qa0.x, v0[0], v0[1]); unp(qa0.y, v0[2], v0[3]);
        unp(qa0.z, v0[4], v0[5]); unp(qa0.w, v0[6], v0[7]);
        unp(qa1.x, v1[0], v1[1]); unp(qa1.y, v1[2], v1[3]);
        unp(qa1.z, v1[4], v1[5]); unp(qa1.w, v1[6], v1[7]);
        unp(qa2.x, v2[0], v2[1]); unp(qa2.y, v2[2], v2[3]);
        unp(qa2.z, v2[4], v2[5]); unp(qa2.w, v2[6], v2[7]);

        float d0 = 0.f, d1 = 0.f, d2 = 0.f;
        #pragma unroll
        for (int j = 0; j < 8; ++j) {
            d0 += v0[j] * av0[j];
            d1 += v1[j] * av1[j];
            d2 += v2[j] * av2[j];
        }
        // reduce over the 8 lanes of each capsule group
        #pragma unroll
        for (int s = 1; s <= 4; s <<= 1) {
            d0 += __shfl_xor(d0, s);
            d1 += __shfl_xor(d1, s);
            d2 += __shfl_xor(d2, s);
        }

        float lg0 = d0, lg1 = d1, lg2 = d2;
        if (T == 3) {
            lg0 += lgp[k * C_ + c0];
            lg1 += lgp[k * C_ + 8 + c0];
            if (has2) lg2 += lgp[k * C_ + 16 + c0];
        }
        float m = fmaxf(lg0, lg1);
        if (has2) m = fmaxf(m, lg2);
        #pragma unroll
        for (int s = 32; s >= 1; s >>= 1) m = fmaxf(m, __shfl_xor(m, s));
        const float e0 = __expf(lg0 - m);
        const float e1 = __expf(lg1 - m);
        const float e2 = has2 ? __expf(lg2 - m) : 0.f;
        float sm = isL ? (e0 + e1 + e2) : 0.f;
        #pragma unroll
        for (int s = 32; s >= 1; s >>= 1) sm += __shfl_xor(sm, s);
        const float is = 1.f / sm;
        const float r0 = e0 * is, r1 = e1 * is, r2 = e2 * is;  // r2==0 on lanes>=32

        if (T == 2 && isL) {
            lsp[k * C_ + c0]     = lg0;
            lsp[k * C_ + 8 + c0] = lg1;
            if (has2) lsp[k * C_ + 16 + c0] = lg2;
        }

        #pragma unroll
        for (int j = 0; j < 8; ++j) {
            ac0[j] += r0 * v0[j];
            ac1[j] += r1 * v1[j];
            ac2[j] += r2 * v2[j];
        }
        qa0 = qb0; qa1 = qb1; qa2 = qb2;
    }

    // block reduce (4 waves) -> partial, no atomics
    #pragma unroll
    for (int j = 0; j < 2; ++j) {
        *(float4*)&red[w][off0 + 4 * j] = make_float4(ac0[4*j], ac0[4*j+1], ac0[4*j+2], ac0[4*j+3]);
        *(float4*)&red[w][off1 + 4 * j] = make_float4(ac1[4*j], ac1[4*j+1], ac1[4*j+2], ac1[4*j+3]);
        if (has2)
            *(float4*)&red[w][off0 + 1024 + 4 * j] = make_float4(ac2[4*j], ac2[4*j+1], ac2[4*j+2], ac2[4*j+3]);
    }
    __syncthreads();
    float* pp = partial + ((size_t)b * RSLICE_ + sgrp) * CA_;
    for (int o = t; o < CA_; o += 256)
        pp[o] = red[0][o] + red[1][o] + red[2][o] + red[3][o];
}

// ---------------------------------------------------------------------------
// Reduce partials over S slices, add bias, squash. One block per (b,c).
// ---------------------------------------------------------------------------
__global__ __launch_bounds__(256) void reduce_squash(
    const float* __restrict__ partial,   // [B][S][CA_]
    int S, float scale,
    const float* __restrict__ bias,      // [C,A]
    float* __restrict__ dst)             // [B,C,A]
{
    __shared__ float red[4][A_];
    const int blk = blockIdx.x;          // 640
    const int b = blk / C_;
    const int c = blk % C_;
    const int t = threadIdx.x;
    const int a = t & 63;
    const int sc = t >> 6;

    const float* pp = partial + (size_t)b * S * CA_ + c * A_ + a;
    float s = 0.f;
    for (int si = sc; si < S; si += 4) s += pp[(size_t)si * CA_];
    red[sc][a] = s;
    __syncthreads();
    if (t < 64) {
        const float p = (red[0][a] + red[1][a] + red[2][a] + red[3][a]) * scale
                      + bias[c * A_ + a];
        float sq = p * p;
        #pragma unroll
        for (int sh = 32; sh >= 1; sh >>= 1) sq += __shfl_xor(sq, sh);
        dst[((size_t)b * C_ + c) * A_ + a] = p * sqrtf(sq) / (1.f + sq);
    }
}

// ---------------------------------------------------------------------------
extern "C" void kernel_launch(void* const* d_in, const int* in_sizes, int n_in,
                              void* d_out, int out_size, void* d_ws, size_t ws_size,
                              hipStream_t stream) {
    const float* x    = (const float*)d_in[0];
    const float* W    = (const float*)d_in[1];
    const float* bias = (const float*)d_in[2];
    float* out = (float*)d_out;

    // workspace layout (~287 MB)
    char* ws = (char*)d_ws;
    u16*   votes   = (u16*)ws;                                   // 262,144,000 B
    float* logits  = (float*)(ws + 262144000ull);                //   8,192,000 B
    float* partial = (float*)(ws + 262144000ull + 8192000ull);   //  16,384,000 B
    float* act     = (float*)(ws + 262144000ull + 8192000ull + 16384000ull);

    // iter 1: votes + uniform-route partial sums; squash with scale 1/20
    votes_kernel<<<NGRP_ * 10, 256, 0, stream>>>(x, W, votes, partial);
    reduce_squash<<<B_ * C_, 256, 0, stream>>>(partial, NGRP_, 1.f / (float)C_, bias, act);

    // iter 2
    route_kernel<2><<<B_ * RSLICE_, 256, 0, stream>>>(votes, act, nullptr, logits, partial);
    reduce_squash<<<B_ * C_, 256, 0, stream>>>(partial, RSLICE_, 1.f, bias, act);

    // iter 3 (its logits update is dead in the reference)
    route_kernel<3><<<B_ * RSLICE_, 256, 0, stream>>>(votes, act, logits, nullptr, partial);
    reduce_squash<<<B_ * C_, 256, 0, stream>>>(partial, RSLICE_, 1.f, bias, out);
}